// Round 12
// baseline (233.477 us; speedup 1.0000x reference)
//
#include <hip/hip_runtime.h>
#include <float.h>

// Problem constants
#define N_PTS    32768       // 8*16*16*16 spatial positions
#define N_CODES  2048
#define DIM      256
#define S_STRIDE 4096        // d*h*w stride of channel dim in z (floats)
#define B_STRIDE 1048576     // per-batch stride in z (256*4096 floats)
#define N_ELEM   8388608     // total z elements

#define MARGIN   8e-4f       // >= 2x |screen-score - np-score| bound (validated R5-R7)

// ws layout (bytes), 512-aligned
#define WS_PARTIAL 0          // float[64]
#define WS_E2      512        // float[2048]             -> 8704
#define WS_EB      8704       // bf16[2048*256] 1 MB     -> 1057280
#define WS_ZT      1057280    // bf16[32768*256] 16.8 MB -> 17834496
#define WS_TMIN    17834496   // float[16][32768][8] 16.8MB -> 34611712
#define WS_STATS   34611712   // float[16][32768][4] 8.4MB -> 43000320
// embp (2 MB, float4-permuted emb for the exact dot) OVERLAYS WS_ZT: zt is
// dead after screen_kernel; perm_emb_kernel runs between screen and exact.
#define WS_EMBP    WS_ZT

typedef unsigned short ushort_t;
typedef short bf16x8 __attribute__((ext_vector_type(8)));
typedef float f32x4 __attribute__((ext_vector_type(4)));

__device__ __forceinline__ ushort_t f2bf(float v) {   // RNE fp32->bf16 (no NaN in data)
    const unsigned u = __float_as_uint(v);
    return (ushort_t)((u + 0x7FFFu + ((u >> 16) & 1u)) >> 16);
}

__device__ __forceinline__ void async_copy16(void* lds, const void* g) {
    __builtin_amdgcn_global_load_lds(
        (const __attribute__((address_space(1))) unsigned int*)g,
        (__attribute__((address_space(3))) unsigned int*)lds, 16, 0, 0);
}

__device__ __forceinline__ void nt_store4(float* p, f32x4 v) {
    __builtin_nontemporal_store(v, reinterpret_cast<f32x4*>(p));
}

// emb fp32 [k][256] -> bf16 eb [k][256] (coalesced)
__global__ void conv_emb_kernel(const float* __restrict__ emb, ushort_t* __restrict__ eb) {
    const int gid = blockIdx.x * 256 + threadIdx.x;   // 512 blocks: 2048 codes x 64 float4
    const int k = gid >> 6, c4 = gid & 63;
    const float4 u = *reinterpret_cast<const float4*>(emb + (size_t)k * DIM + c4 * 4);
    ushort4 v; v.x = f2bf(u.x); v.y = f2bf(u.y); v.z = f2bf(u.z); v.w = f2bf(u.w);
    *reinterpret_cast<ushort4*>(eb + (size_t)k * DIM + c4 * 4) = v;
}

// emb fp32 [2048][256] -> embp float4[(g*64+c4)*16+ql] = emb[g*16+ql][c4*4..+3].
__global__ void perm_emb_kernel(const float* __restrict__ emb, float* __restrict__ embp) {
    const int gid = blockIdx.x * 256 + threadIdx.x;   // 512 blocks: 131072 float4s
    const int ql = gid & 15, c4 = (gid >> 4) & 63, g = gid >> 10;
    const float4 u = reinterpret_cast<const float4*>(emb)[(size_t)(g * 16 + ql) * 64 + c4];
    reinterpret_cast<float4*>(embp)[gid] = u;         // gid == (g*64+c4)*16+ql
}

// e2[k] = np-pairwise sum of emb[k][:]^2; also zeroes loss partials.
__global__ void e2p_kernel(const float* __restrict__ emb, float* __restrict__ e2,
                           float* __restrict__ partial) {
    const int k = blockIdx.x * 256 + threadIdx.x;
    if (blockIdx.x == 0 && threadIdx.x < 64) partial[threadIdx.x] = 0.f;
    const float* base = emb + (size_t)k * DIM;
    float half[2];
    #pragma unroll
    for (int h = 0; h < 2; ++h) {
        float r[8];
        #pragma unroll
        for (int j = 0; j < 8; ++j) { const float v = base[h * 128 + j]; r[j] = __fmul_rn(v, v); }
        for (int t = 8; t < 128; t += 8)
            #pragma unroll
            for (int j = 0; j < 8; ++j) {
                const float v = base[h * 128 + t + j];
                r[j] = __fadd_rn(r[j], __fmul_rn(v, v));
            }
        half[h] = __fadd_rn(__fadd_rn(__fadd_rn(r[0], r[1]), __fadd_rn(r[2], r[3])),
                            __fadd_rn(__fadd_rn(r[4], r[5]), __fadd_rn(r[6], r[7])));
    }
    e2[k] = __fadd_rn(half[0], half[1]);
}

// z [8][256][4096] fp32 -> z_t [n][c] bf16 (pitch 256), 64x64 LDS transpose tiles.
__global__ void transpose_kernel(const float* __restrict__ z, ushort_t* __restrict__ zt) {
    __shared__ ushort_t lt[64][72];
    const int bx = blockIdx.x;            // 2048 = 8 b x 4 cg x 64 sg
    const int b = bx >> 8, cg = (bx >> 6) & 3, sg = bx & 63;
    const int c0 = cg * 64, s0 = sg * 64;
    const int t = threadIdx.x;
    {
        const int cl = t >> 4, s4 = t & 15;
        #pragma unroll
        for (int j = 0; j < 4; ++j) {
            const int c = cl + 16 * j;
            const float4 u = *reinterpret_cast<const float4*>(
                z + (size_t)b * B_STRIDE + (size_t)(c0 + c) * S_STRIDE + s0 + s4 * 4);
            ushort4 v; v.x = f2bf(u.x); v.y = f2bf(u.y); v.z = f2bf(u.z); v.w = f2bf(u.w);
            *reinterpret_cast<ushort4*>(&lt[c][s4 * 4]) = v;
        }
    }
    __syncthreads();
    {
        const int sl = t >> 4, c4 = t & 15;
        #pragma unroll
        for (int j = 0; j < 4; ++j) {
            const int s = sl + 16 * j;
            ushort4 v;
            v.x = lt[c4 * 4 + 0][s]; v.y = lt[c4 * 4 + 1][s];
            v.z = lt[c4 * 4 + 2][s]; v.w = lt[c4 * 4 + 3][s];
            *reinterpret_cast<ushort4*>(zt + (size_t)(b * 4096 + s0 + s) * DIM + c0 + c4 * 4) = v;
        }
    }
}

// Screen GEMM, R11 structure (unchanged): R8 GEMM + per-point (min, argmin,
// 2ndmin) stats for the exact gap-shortcut. tmin path bit-identical.
__global__ __launch_bounds__(256, 4) void screen_kernel(
    const ushort_t* __restrict__ zt, const ushort_t* __restrict__ eb,
    const float* __restrict__ e2, float* __restrict__ tmin,
    float* __restrict__ stats)
{
    __shared__ char lds[32768];          // [Z0 8K | E0 8K | Z1 8K | E1 8K]
    __shared__ float e2s[128];
    const int tid = threadIdx.x;
    const int x = blockIdx.x;            // 4096 = 8 xcd-chunk x 32 bm-off x 16 bn
    const int bm = (x & 7) * 32 + ((x >> 3) & 31), bn = x >> 8;
    const int n0 = bm * 128, k0 = bn * 128;
    if (tid < 128) e2s[tid] = e2[k0 + tid];
    const int wv = tid >> 6, lane = tid & 63;
    const int col = lane & 15, quad = lane >> 4;
    const int pcr = quad ^ ((col >> 1) & 3);

    f32x4 acc[2][8];
    #pragma unroll
    for (int j = 0; j < 2; ++j)
        #pragma unroll
        for (int i = 0; i < 8; ++i) acc[j][i] = (f32x4){0.f, 0.f, 0.f, 0.f};

    #define STAGE(kc_, half_)                                                       \
        {                                                                           \
            const int base_ = (half_) * 16384;                                      \
            _Pragma("unroll")                                                       \
            for (int it = 0; it < 4; ++it) {                                        \
                const int L = tid + it * 256;                                       \
                if (L < 512) {                                                      \
                    const int row = L >> 2, pc = L & 3, c = pc ^ ((row >> 1) & 3);  \
                    async_copy16(lds + base_ + L * 16,                              \
                                 zt + ((size_t)(n0 + row) * DIM + (kc_) * 32 + c * 8)); \
                } else {                                                            \
                    const int L2 = L - 512;                                         \
                    const int row = L2 >> 2, pc = L2 & 3, c = pc ^ ((row >> 1) & 3);\
                    async_copy16(lds + base_ + 8192 + L2 * 16,                      \
                                 eb + ((size_t)(k0 + row) * DIM + (kc_) * 32 + c * 8)); \
                }                                                                   \
            }                                                                       \
        }

    STAGE(0, 0);
    __syncthreads();                     // cold drain (once)
    #pragma unroll
    for (int kc = 0; kc < 8; ++kc) {
        const int cur = kc & 1;
        if (kc < 7) STAGE(kc + 1, cur ^ 1);          // issue, don't wait
        {
            const char* zb = lds + cur * 16384;      // zt region (8 KB)
            const char* ebb = zb + 8192;             // eb region (8 KB)
            bf16x8 af[2];
            #pragma unroll
            for (int j = 0; j < 2; ++j) {
                const int crow = wv * 32 + j * 16 + col;     // code row in tile
                af[j] = *reinterpret_cast<const bf16x8*>(ebb + (crow * 4 + pcr) * 16);
            }
            #pragma unroll
            for (int i = 0; i < 8; ++i) {
                const int prow = i * 16 + col;               // point row in tile
                const bf16x8 bq = *reinterpret_cast<const bf16x8*>(zb + (prow * 4 + pcr) * 16);
                #pragma unroll
                for (int j = 0; j < 2; ++j)
                    acc[j][i] = __builtin_amdgcn_mfma_f32_16x16x32_bf16(af[j], bq, acc[j][i], 0, 0, 0);
            }
        }
        __syncthreads();
    }
    #undef STAGE

    // epilogue. D rows = codes (quad*4+r per lane), cols = points (col lane).
    float* res  = reinterpret_cast<float*>(lds);          // [128 pts][12] 6 KB
    float* sbuf = reinterpret_cast<float*>(lds + 8192);   // [128 pts][12]: 4 wv x (m1,i1,m2)
    float ej[2][4];                                       // e2 for codes wv*32+j*16+quad*4+r
    #pragma unroll
    for (int j = 0; j < 2; ++j) {
        const f32x4 e4 = *reinterpret_cast<const f32x4*>(&e2s[wv * 32 + j * 16 + quad * 4]);
        ej[j][0] = e4[0]; ej[j][1] = e4[1]; ej[j][2] = e4[2]; ej[j][3] = e4[3];
    }
    // group-min path (unchanged)
    #pragma unroll
    for (int j = 0; j < 2; ++j) {
        #pragma unroll
        for (int i = 0; i < 8; ++i) {
            float tm[4];
            #pragma unroll
            for (int r = 0; r < 4; ++r) tm[r] = fmaf(-2.f, acc[j][i][r], ej[j][r]);
            float m = fminf(fminf(tm[0], tm[1]), fminf(tm[2], tm[3]));
            m = fminf(m, __shfl_xor(m, 16));
            m = fminf(m, __shfl_xor(m, 32));
            if (quad == 0)
                res[(i * 16 + col) * 12 + wv * 2 + j] = m;
        }
    }
    // stats path: per point (min, argmin, 2nd-min) over this wave's 32 codes
    #pragma unroll
    for (int i = 0; i < 8; ++i) {
        float m1 = FLT_MAX, m2 = FLT_MAX; int i1 = 0;
        #pragma unroll
        for (int j = 0; j < 2; ++j) {
            #pragma unroll
            for (int r = 0; r < 4; ++r) {           // ascending code index
                const float v = fmaf(-2.f, acc[j][i][r], ej[j][r]);
                const int idx = k0 + wv * 32 + j * 16 + quad * 4 + r;
                if (v < m1) { m2 = m1; m1 = v; i1 = idx; }
                else if (v < m2) { m2 = v; }
            }
        }
        #pragma unroll
        for (int off = 16; off <= 32; off <<= 1) {  // combine across quads
            const float om1 = __shfl_xor(m1, off);
            const float om2 = __shfl_xor(m2, off);
            const int   oi1 = __shfl_xor(i1, off);
            if (om1 < m1) { m2 = fminf(om2, m1); m1 = om1; i1 = oi1; }
            else          { m2 = fminf(m2, om1); }
        }
        if (quad == 0) {
            const int p = i * 16 + col;
            sbuf[p * 12 + wv * 3 + 0] = m1;
            sbuf[p * 12 + wv * 3 + 1] = (float)i1;
            sbuf[p * 12 + wv * 3 + 2] = m2;
        }
    }
    __syncthreads();
    {   // coalesced tmin store, layout [bn][n][8]
        const int p = tid >> 1, h = tid & 1;
        const f32x4 v = *reinterpret_cast<const f32x4*>(&res[p * 12 + h * 4]);
        *reinterpret_cast<f32x4*>(
            &tmin[((size_t)bn * N_PTS + n0 + p) * 8 + h * 4]) = v;
    }
    if (tid < 128) {  // combine 4 wave-triples (ascending wv; ties -> gap 0) + store stats
        const int p = tid;
        float m1 = sbuf[p * 12 + 0], i1 = sbuf[p * 12 + 1], m2 = sbuf[p * 12 + 2];
        #pragma unroll
        for (int w = 1; w < 4; ++w) {
            const float bm1 = sbuf[p * 12 + w * 3 + 0];
            const float bi1 = sbuf[p * 12 + w * 3 + 1];
            const float bm2 = sbuf[p * 12 + w * 3 + 2];
            if (bm1 < m1) { m2 = fminf(m1, bm2); m1 = bm1; i1 = bi1; }
            else          { m2 = fminf(m2, bm1); }
        }
        f32x4 st; st[0] = m1; st[1] = i1; st[2] = m2; st[3] = 0.f;
        *reinterpret_cast<f32x4*>(&stats[((size_t)bn * N_PTS + n0 + p) * 4]) = st;
    }
}

// Fused exact re-resolve + z2 + gather + loss.
// R12: PACKED fallback. Phase 1: per point, gap-test via stats; shortcut
// points finish immediately (gather+loss, no tmin read, no z2). A wave-
// uniform 8-bit slot mask collects fallback points. Phase 2: pop up to 4
// slots per iteration -- one per quad, densely packed (R11's quad-uniform
// skip left 3 quads masked-idle whenever 1 of 4 needed resolve: P=0.7^4
// full-skip only). Resolve path per point is the R8/R11-validated code,
// bit-identical (fresh a[8] tmin loads, same chains, ascending order).
__global__ __launch_bounds__(256, 3) void exact_kernel(
    const float* __restrict__ z, const float* __restrict__ emb,
    const float* __restrict__ embp,
    const float* __restrict__ e2, const float* __restrict__ tmin,
    const float* __restrict__ stats,
    float* __restrict__ outf, float* __restrict__ out_idx, float* __restrict__ partial)
{
    __shared__ float zs[32 * 260];       // [p][c] pitch 260 (33.3 KB)
    const int tid = threadIdx.x;
    const int n0 = blockIdx.x * 32;
    const int b = n0 >> 12, s0 = n0 & 4095;
    {   // coalesced stage: float4 along s (8 lanes x 16B = 128B/channel), 32 ch/pass
        const int tq = tid & 7, cg = tid >> 3;
        for (int c = cg; c < DIM; c += 32) {
            const float4 u = *reinterpret_cast<const float4*>(
                z + (size_t)b * B_STRIDE + (size_t)c * S_STRIDE + s0 + tq * 4);
            zs[(tq * 4 + 0) * 260 + c] = u.x;
            zs[(tq * 4 + 1) * 260 + c] = u.y;
            zs[(tq * 4 + 2) * 260 + c] = u.z;
            zs[(tq * 4 + 3) * 260 + c] = u.w;
        }
    }
    __syncthreads();
    const int wv = tid >> 6, lane = tid & 63;
    const int quad = lane >> 4, ql = lane & 15;
    float lossacc = 0.f;

// gather z_q row (out[n][c] = emb[idx[n]][c]) + loss, float4 per quad-lane
#define GATHER(bk_, n_, zr_)                                                   \
    {                                                                          \
        const float* eq = emb + (size_t)(bk_) * DIM;                           \
        float* op = outf + (size_t)(n_) * DIM;                                 \
        _Pragma("unroll")                                                      \
        for (int jj = 0; jj < 4; ++jj) {                                       \
            const int c = (jj * 16 + ql) * 4;                                  \
            const float4 q4 = *reinterpret_cast<const float4*>(eq + c);        \
            f32x4 q; q[0] = q4.x; q[1] = q4.y; q[2] = q4.z; q[3] = q4.w;       \
            nt_store4(op + c, q);                                              \
            float d;                                                           \
            d = q4.x - (zr_)[c + 0]; lossacc = fmaf(d, d, lossacc);            \
            d = q4.y - (zr_)[c + 1]; lossacc = fmaf(d, d, lossacc);            \
            d = q4.z - (zr_)[c + 2]; lossacc = fmaf(d, d, lossacc);            \
            d = q4.w - (zr_)[c + 3]; lossacc = fmaf(d, d, lossacc);            \
        }                                                                      \
        if (ql == 0) out_idx[n_] = (float)(bk_);                               \
    }

    // ---- Phase 1: flags + shortcut completion ----
    int fb_mask = 0;                     // wave-uniform: bit (t*4+quad) = fallback
    #pragma unroll
    for (int t = 0; t < 2; ++t) {
        const int p = wv * 8 + t * 4 + quad;
        const int n = n0 + p;
        const f32x4 st = *reinterpret_cast<const f32x4*>(
            &stats[((size_t)ql * N_PTS + n) * 4]);     // lane ql <-> block bn=ql
        float m1 = st[0], i1f = st[1], m2 = st[2];
        #pragma unroll
        for (int off = 1; off < 16; off <<= 1) {       // full quad butterfly
            const float om1 = __shfl_xor(m1, off);
            const float oi1 = __shfl_xor(i1f, off);
            const float om2 = __shfl_xor(m2, off);
            if (om1 < m1) { m2 = fminf(m1, om2); m1 = om1; i1f = oi1; }
            else          { m2 = fminf(m2, om1); }
        }
        const bool shortcut = (m2 - m1 > MARGIN);      // quad-uniform
        const unsigned long long bal = __ballot(!shortcut);
        const int bits4 = (int)(((bal >> 0) & 1) | (((bal >> 16) & 1) << 1) |
                                (((bal >> 32) & 1) << 2) | (((bal >> 48) & 1) << 3));
        fb_mask |= bits4 << (t * 4);
        if (shortcut) {
            const int bk = (int)i1f;
            const float* zr = &zs[p * 260];
            GATHER(bk, n, zr);
        }
    }

    // ---- Phase 2: packed fallback resolve (<=4 points per iteration) ----
    while (fb_mask) {                    // wave-uniform loop
        int sel[4];
        #pragma unroll
        for (int sl = 0; sl < 4; ++sl) {
            int s = -1;
            if (fb_mask) { s = __ffs(fb_mask) - 1; fb_mask &= fb_mask - 1; }
            sel[sl] = s;
        }
        const int myslot = sel[quad];    // quad-uniform
        const int p = wv * 8 + (myslot >= 0 ? myslot : 0);
        const int n = n0 + p;
        const float* zr = &zs[p * 260];
        unsigned long long M0 = 0ull, M1 = 0ull;
        float z2n = 0.f;
        if (myslot >= 0) {
            // group minima for this point (L2-hot; only fallback points read tmin)
            float a[8];
            #pragma unroll
            for (int i = 0; i < 8; ++i)
                a[i] = tmin[((size_t)(i * 2 + (ql >> 3)) * N_PTS + n) * 8 + (ql & 7)];
            // np-exact z2 (validated chain, per quad)
            const int h = ql >> 3, j = ql & 7;
            float v0 = zr[h * 128 + j];
            float r = __fmul_rn(v0, v0);
            #pragma unroll
            for (int t2 = 1; t2 < 16; ++t2) {
                const float v = zr[h * 128 + j + 8 * t2];
                r = __fadd_rn(r, __fmul_rn(v, v));
            }
            { float v = __shfl_xor(r, 1); r = __fadd_rn(r, v); }
            { float v = __shfl_xor(r, 2); r = __fadd_rn(r, v); }
            { float v = __shfl_xor(r, 4); r = __fadd_rn(r, v); }
            z2n = __fadd_rn(__shfl(r, quad * 16), __shfl(r, quad * 16 + 8));
            float mn = fminf(fminf(fminf(a[0], a[1]), fminf(a[2], a[3])),
                             fminf(fminf(a[4], a[5]), fminf(a[6], a[7])));
            #pragma unroll
            for (int off = 1; off < 16; off <<= 1) mn = fminf(mn, __shfl_xor(mn, off));
            const float thr = mn + MARGIN;
            #pragma unroll
            for (int i = 0; i < 8; ++i) {       // ascending group order preserved
                const unsigned long long bal = __ballot(a[i] <= thr);
                const unsigned long long bits = (bal >> (quad * 16)) & 0xFFFFull;
                if (i < 4) M0 |= bits << (i * 16);
                else       M1 |= bits << ((i - 4) * 16);
            }
        }
        float bs = FLT_MAX; int bkf = 0x7FFFFFFF;
        while (__any((M0 | M1) != 0ull)) {
            int myt = -1;                       // quad-uniform next group, ascending
            if (M0) { myt = __ffsll(M0) - 1; M0 &= M0 - 1; }
            else if (M1) { myt = 64 + __ffsll(M1) - 1; M1 &= M1 - 1; }
            if (myt >= 0) {
                const int kg = myt * 16 + ql;
                const float e2k = e2[kg];
                const float4* gp = reinterpret_cast<const float4*>(embp)
                                   + (size_t)myt * 1024 + ql;
                float4 pre[8];
                #pragma unroll
                for (int s8 = 0; s8 < 8; ++s8) pre[s8] = gp[s8 * 16];
                float dot = 0.f;                // np-exact ascending-c fmaf chain
                #pragma unroll
                for (int seg = 0; seg < 8; ++seg) {
                    float4 cur[8];
                    #pragma unroll
                    for (int s8 = 0; s8 < 8; ++s8) cur[s8] = pre[s8];
                    if (seg < 7) {
                        #pragma unroll
                        for (int s8 = 0; s8 < 8; ++s8)
                            pre[s8] = gp[(seg + 1) * 128 + s8 * 16];
                    }
                    #pragma unroll
                    for (int s8 = 0; s8 < 8; ++s8) {
                        const int c4 = seg * 8 + s8;
                        const float4 zv = *reinterpret_cast<const float4*>(zr + c4 * 4);
                        dot = fmaf(zv.x, cur[s8].x, dot);
                        dot = fmaf(zv.y, cur[s8].y, dot);
                        dot = fmaf(zv.z, cur[s8].z, dot);
                        dot = fmaf(zv.w, cur[s8].w, dot);
                    }
                }
                const float A = __fadd_rn(z2n, e2k);
                const float s = __fsub_rn(A, __fmul_rn(2.f, dot));
                if (s < bs || (s == bs && kg < bkf)) { bs = s; bkf = kg; }
            }
        }
        #pragma unroll
        for (int off = 1; off < 16; off <<= 1) {   // lex-min within quad = np.argmin
            const float os = __shfl_xor(bs, off);
            const int ok = __shfl_xor(bkf, off);
            if (os < bs || (os == bs && ok < bkf)) { bs = os; bkf = ok; }
        }
        if (myslot >= 0) {
            GATHER(bkf, n, zr);
        }
    }
    #undef GATHER

    #pragma unroll
    for (int off = 1; off < 64; off <<= 1) lossacc += __shfl_xor(lossacc, off);
    if (lane == 0) atomicAdd(&partial[blockIdx.x & 63], lossacc);
}

__global__ void finalize_kernel(const float* __restrict__ partial, float* __restrict__ out_loss) {
    float v = partial[threadIdx.x];          // 64 threads
    #pragma unroll
    for (int off = 1; off < 64; off <<= 1) v += __shfl_xor(v, off);
    if (threadIdx.x == 0)
        *out_loss = v * 1.25f / (float)N_ELEM;   // (1+BETA)*mean
}

extern "C" void kernel_launch(void* const* d_in, const int* in_sizes, int n_in,
                              void* d_out, int out_size, void* d_ws, size_t ws_size,
                              hipStream_t stream) {
    const float* z = (const float*)d_in[0];
    const float* emb = (const float*)d_in[1];
    char* ws = (char*)d_ws;
    float* partial = (float*)(ws + WS_PARTIAL);
    float* e2 = (float*)(ws + WS_E2);
    ushort_t* eb = (ushort_t*)(ws + WS_EB);
    ushort_t* zt = (ushort_t*)(ws + WS_ZT);
    float* embp = (float*)(ws + WS_EMBP);    // overlays zt (dead after screen)
    float* tmin = (float*)(ws + WS_TMIN);
    float* stats = (float*)(ws + WS_STATS);
    float* outf = (float*)d_out;
    float* out_loss = outf + N_ELEM;
    float* out_idx = outf + N_ELEM + 1;

    conv_emb_kernel<<<512, 256, 0, stream>>>(emb, eb);
    e2p_kernel<<<N_CODES / 256, 256, 0, stream>>>(emb, e2, partial);
    transpose_kernel<<<2048, 256, 0, stream>>>(z, zt);
    screen_kernel<<<4096, 256, 0, stream>>>(zt, eb, e2, tmin, stats);
    perm_emb_kernel<<<512, 256, 0, stream>>>(emb, embp);   // after screen: reuses zt region
    exact_kernel<<<N_PTS / 32, 256, 0, stream>>>(z, emb, embp, e2, tmin, stats,
                                                 outf, out_idx, partial);
    finalize_kernel<<<1, 64, 0, stream>>>(partial, out_loss);
}

// Round 13
// 199.764 us; speedup vs baseline: 1.1688x; 1.1688x over previous
//
#include <hip/hip_runtime.h>
#include <float.h>

// Problem constants
#define N_PTS    32768       // 8*16*16*16 spatial positions
#define N_CODES  2048
#define DIM      256
#define S_STRIDE 4096        // d*h*w stride of channel dim in z (floats)
#define B_STRIDE 1048576     // per-batch stride in z (256*4096 floats)
#define N_ELEM   8388608     // total z elements

#define MARGIN   8e-4f       // >= 2x |screen-score - np-score| bound (validated R5-R7)

// ws layout (bytes), 512-aligned
#define WS_PARTIAL 0          // float[64]
#define WS_E2      512        // float[2048]             -> 8704
#define WS_EB      8704       // bf16[2048*256] 1 MB     -> 1057280
#define WS_ZT      1057280    // bf16[32768*256] 16.8 MB -> 17834496
#define WS_TMIN    17834496   // float[16][32768][8] 16.8MB -> 34611712
#define WS_EMBP    34611712   // float[2048*256] 2 MB    -> 36708864 (own region; no overlay)

typedef unsigned short ushort_t;
typedef short bf16x8 __attribute__((ext_vector_type(8)));
typedef float f32x4 __attribute__((ext_vector_type(4)));

__device__ __forceinline__ ushort_t f2bf(float v) {   // RNE fp32->bf16 (no NaN in data)
    const unsigned u = __float_as_uint(v);
    return (ushort_t)((u + 0x7FFFu + ((u >> 16) & 1u)) >> 16);
}

__device__ __forceinline__ void async_copy16(void* lds, const void* g) {
    __builtin_amdgcn_global_load_lds(
        (const __attribute__((address_space(1))) unsigned int*)g,
        (__attribute__((address_space(3))) unsigned int*)lds, 16, 0, 0);
}

__device__ __forceinline__ void nt_store4(float* p, f32x4 v) {
    __builtin_nontemporal_store(v, reinterpret_cast<f32x4*>(p));
}

// Fused prep, R13: blocks 0..511 = emb prep (conv->bf16 eb, np-exact e2,
// fp32 permute->embp, reading emb ONCE through LDS); blocks 512..2559 =
// z transpose (identical body to the former transpose_kernel). Cuts 7
// launches to 4 and removes two redundant 2 MB emb passes. All numerics
// are the validated paths verbatim (e2 chain consumes bit-identical fp32).
__global__ void prep_kernel(const float* __restrict__ z, const float* __restrict__ emb,
                            ushort_t* __restrict__ eb, float* __restrict__ embp,
                            float* __restrict__ e2, float* __restrict__ partial,
                            ushort_t* __restrict__ zt) {
    __shared__ ushort_t lt[64][72];                  // 9216 B; emb branch aliases 4 KB
    const int bx = blockIdx.x;
    const int tid = threadIdx.x;
    if (bx < 512) {
        float* er = reinterpret_cast<float*>(lt);    // [4][256]
        if (bx == 0 && tid < 64) partial[tid] = 0.f;
        const int kk = tid >> 6, c4 = tid & 63;      // code offset 0..3, float4 idx
        const int k = bx * 4 + kk;
        const float4 u = *reinterpret_cast<const float4*>(emb + (size_t)k * DIM + c4 * 4);
        ushort4 v; v.x = f2bf(u.x); v.y = f2bf(u.y); v.z = f2bf(u.z); v.w = f2bf(u.w);
        *reinterpret_cast<ushort4*>(eb + (size_t)k * DIM + c4 * 4) = v;
        // embp[(g*64+c4)*16+ql] = emb[g*16+ql][c4*4..+3]  (same permutation as before)
        reinterpret_cast<float4*>(embp)[((size_t)(k >> 4) * 64 + c4) * 16 + (k & 15)] = u;
        *reinterpret_cast<float4*>(&er[kk * 256 + c4 * 4]) = u;
        __syncthreads();
        if (tid < 4) {                               // np-pairwise e2 chain (validated)
            const float* base = &er[tid * 256];
            float half[2];
            #pragma unroll
            for (int h = 0; h < 2; ++h) {
                float r[8];
                #pragma unroll
                for (int j = 0; j < 8; ++j) { const float vv = base[h * 128 + j]; r[j] = __fmul_rn(vv, vv); }
                for (int t = 8; t < 128; t += 8)
                    #pragma unroll
                    for (int j = 0; j < 8; ++j) {
                        const float vv = base[h * 128 + t + j];
                        r[j] = __fadd_rn(r[j], __fmul_rn(vv, vv));
                    }
                half[h] = __fadd_rn(__fadd_rn(__fadd_rn(r[0], r[1]), __fadd_rn(r[2], r[3])),
                                    __fadd_rn(__fadd_rn(r[4], r[5]), __fadd_rn(r[6], r[7])));
            }
            e2[bx * 4 + tid] = __fadd_rn(half[0], half[1]);
        }
    } else {
        // z [8][256][4096] fp32 -> z_t [n][c] bf16 (pitch 256), 64x64 LDS tiles.
        const int bx2 = bx - 512;                    // 2048 = 8 b x 4 cg x 64 sg
        const int b = bx2 >> 8, cg = (bx2 >> 6) & 3, sg = bx2 & 63;
        const int c0 = cg * 64, s0 = sg * 64;
        {
            const int cl = tid >> 4, s4 = tid & 15;
            #pragma unroll
            for (int j = 0; j < 4; ++j) {
                const int c = cl + 16 * j;
                const float4 u = *reinterpret_cast<const float4*>(
                    z + (size_t)b * B_STRIDE + (size_t)(c0 + c) * S_STRIDE + s0 + s4 * 4);
                ushort4 v; v.x = f2bf(u.x); v.y = f2bf(u.y); v.z = f2bf(u.z); v.w = f2bf(u.w);
                *reinterpret_cast<ushort4*>(&lt[c][s4 * 4]) = v;
            }
        }
        __syncthreads();
        {
            const int sl = tid >> 4, c4 = tid & 15;
            #pragma unroll
            for (int j = 0; j < 4; ++j) {
                const int s = sl + 16 * j;
                ushort4 v;
                v.x = lt[c4 * 4 + 0][s]; v.y = lt[c4 * 4 + 1][s];
                v.z = lt[c4 * 4 + 2][s]; v.w = lt[c4 * 4 + 3][s];
                *reinterpret_cast<ushort4*>(zt + (size_t)(b * 4096 + s0 + s) * DIM + c0 + c4 * 4) = v;
            }
        }
    }
}

// Screen GEMM, R8 exactly (best-measured config): 128 pts x 128 codes x
// BK=32, 4 blocks/CU, swapped operands (A=eb codes, B=zt points; in-lane
// group-min), 2-phase prefetch, XCD-chunked order, [bn][n][8] tmin layout
// (contiguous 4 KB/block store). Stats path removed (R11/12: +10 us in
// screen, zero gain in exact).
__global__ __launch_bounds__(256, 4) void screen_kernel(
    const ushort_t* __restrict__ zt, const ushort_t* __restrict__ eb,
    const float* __restrict__ e2, float* __restrict__ tmin)
{
    __shared__ char lds[32768];          // [Z0 8K | E0 8K | Z1 8K | E1 8K]; res overlays [0,6144)
    __shared__ float e2s[128];
    const int tid = threadIdx.x;
    const int x = blockIdx.x;            // 4096 = 8 xcd-chunk x 32 bm-off x 16 bn
    const int bm = (x & 7) * 32 + ((x >> 3) & 31), bn = x >> 8;
    const int n0 = bm * 128, k0 = bn * 128;
    if (tid < 128) e2s[tid] = e2[k0 + tid];
    const int wv = tid >> 6, lane = tid & 63;
    const int col = lane & 15, quad = lane >> 4;
    const int pcr = quad ^ ((col >> 1) & 3);

    // acc[j][i]: j = code-16-block (codes wv*32 + j*16), i = point-16-block.
    f32x4 acc[2][8];
    #pragma unroll
    for (int j = 0; j < 2; ++j)
        #pragma unroll
        for (int i = 0; i < 8; ++i) acc[j][i] = (f32x4){0.f, 0.f, 0.f, 0.f};

    #define STAGE(kc_, half_)                                                       \
        {                                                                           \
            const int base_ = (half_) * 16384;                                      \
            _Pragma("unroll")                                                       \
            for (int it = 0; it < 4; ++it) {                                        \
                const int L = tid + it * 256;                                       \
                if (L < 512) {                                                      \
                    const int row = L >> 2, pc = L & 3, c = pc ^ ((row >> 1) & 3);  \
                    async_copy16(lds + base_ + L * 16,                              \
                                 zt + ((size_t)(n0 + row) * DIM + (kc_) * 32 + c * 8)); \
                } else {                                                            \
                    const int L2 = L - 512;                                         \
                    const int row = L2 >> 2, pc = L2 & 3, c = pc ^ ((row >> 1) & 3);\
                    async_copy16(lds + base_ + 8192 + L2 * 16,                      \
                                 eb + ((size_t)(k0 + row) * DIM + (kc_) * 32 + c * 8)); \
                }                                                                   \
            }                                                                       \
        }

    STAGE(0, 0);
    __syncthreads();                     // cold drain (once)
    #pragma unroll
    for (int kc = 0; kc < 8; ++kc) {
        const int cur = kc & 1;
        if (kc < 7) STAGE(kc + 1, cur ^ 1);          // issue, don't wait
        {   // compute current half: A-frags = eb code rows, B-frags = zt point rows
            const char* zb = lds + cur * 16384;      // zt region (8 KB)
            const char* ebb = zb + 8192;             // eb region (8 KB)
            bf16x8 af[2];
            #pragma unroll
            for (int j = 0; j < 2; ++j) {
                const int crow = wv * 32 + j * 16 + col;     // code row in tile
                af[j] = *reinterpret_cast<const bf16x8*>(ebb + (crow * 4 + pcr) * 16);
            }
            #pragma unroll
            for (int i = 0; i < 8; ++i) {
                const int prow = i * 16 + col;               // point row in tile
                const bf16x8 bq = *reinterpret_cast<const bf16x8*>(zb + (prow * 4 + pcr) * 16);
                #pragma unroll
                for (int j = 0; j < 2; ++j)
                    acc[j][i] = __builtin_amdgcn_mfma_f32_16x16x32_bf16(af[j], bq, acc[j][i], 0, 0, 0);
            }
        }
        __syncthreads();                 // drains prefetch (flew during MFMA)
    }
    #undef STAGE

    // epilogue: D rows = codes (quad*4+r per lane), cols = points (col lane).
    // Group-of-16-codes min: 3 in-lane fmin over regs + 2 cross-quad shfl.
    float* res = reinterpret_cast<float*>(lds);      // [128 pts][pitch 12] 6 KB (staging dead)
    float ej[2][4];                                  // e2 for codes wv*32+j*16+quad*4+r
    #pragma unroll
    for (int j = 0; j < 2; ++j) {
        const f32x4 e4 = *reinterpret_cast<const f32x4*>(&e2s[wv * 32 + j * 16 + quad * 4]);
        ej[j][0] = e4[0]; ej[j][1] = e4[1]; ej[j][2] = e4[2]; ej[j][3] = e4[3];
    }
    #pragma unroll
    for (int j = 0; j < 2; ++j) {
        #pragma unroll
        for (int i = 0; i < 8; ++i) {
            float tm[4];
            #pragma unroll
            for (int r = 0; r < 4; ++r) tm[r] = fmaf(-2.f, acc[j][i][r], ej[j][r]);
            float m = fminf(fminf(tm[0], tm[1]), fminf(tm[2], tm[3]));
            m = fminf(m, __shfl_xor(m, 16));
            m = fminf(m, __shfl_xor(m, 32));         // min over all 16 codes of group
            if (quad == 0)
                res[(i * 16 + col) * 12 + wv * 2 + j] = m;   // group index 0..7
        }
    }
    __syncthreads();
    {   // coalesced tmin store, layout [bn][n][8]: block writes 4 KB contiguous.
        const int p = tid >> 1, h = tid & 1;         // 256 threads x 4 floats
        const f32x4 v = *reinterpret_cast<const f32x4*>(&res[p * 12 + h * 4]);
        *reinterpret_cast<f32x4*>(
            &tmin[((size_t)bn * N_PTS + n0 + p) * 8 + h * 4]) = v;
    }
}

// Fused exact re-resolve + z2 + gather + loss. R8 version exactly (the
// best-measured exact: 71 us, VGPR 80): 32-pt blocks, quad-parallel points,
// 8x8 segmented-prefetch np-exact fmaf dot, lex-min tie-break, nt out store.
// tmin layout [bn][n][8]: group g = i*16+ql at bn = i*2+(ql>>3), local ql&7.
__global__ __launch_bounds__(256, 3) void exact_kernel(
    const float* __restrict__ z, const float* __restrict__ emb,
    const float* __restrict__ embp,
    const float* __restrict__ e2, const float* __restrict__ tmin,
    float* __restrict__ outf, float* __restrict__ out_idx, float* __restrict__ partial)
{
    __shared__ float zs[32 * 260];       // [p][c] pitch 260 (33.3 KB)
    const int tid = threadIdx.x;
    const int n0 = blockIdx.x * 32;
    const int b = n0 >> 12, s0 = n0 & 4095;
    {   // coalesced stage: float4 along s (8 lanes x 16B = 128B/channel), 32 ch/pass
        const int tq = tid & 7, cg = tid >> 3;
        for (int c = cg; c < DIM; c += 32) {
            const float4 u = *reinterpret_cast<const float4*>(
                z + (size_t)b * B_STRIDE + (size_t)c * S_STRIDE + s0 + tq * 4);
            zs[(tq * 4 + 0) * 260 + c] = u.x;
            zs[(tq * 4 + 1) * 260 + c] = u.y;
            zs[(tq * 4 + 2) * 260 + c] = u.z;
            zs[(tq * 4 + 3) * 260 + c] = u.w;
        }
    }
    __syncthreads();
    const int wv = tid >> 6, lane = tid & 63;
    const int quad = lane >> 4, ql = lane & 15;
    float lossacc = 0.f;

    // hoist all tmin loads: 8 group-minima per lane per round, statically indexed
    float a[2][8];
    #pragma unroll
    for (int t = 0; t < 2; ++t) {
        const int n = n0 + wv * 8 + t * 4 + quad;
        #pragma unroll
        for (int i = 0; i < 8; ++i)
            a[t][i] = __builtin_nontemporal_load(
                tmin + ((size_t)(i * 2 + (ql >> 3)) * N_PTS + n) * 8 + (ql & 7));
    }

    #pragma unroll
    for (int t = 0; t < 2; ++t) {
        const int p = wv * 8 + t * 4 + quad;     // this quad's point
        const int n = n0 + p;
        const float* zr = &zs[p * 260];
        // np-exact z2: the quad's 16 lanes run the 8-accumulator chains,
        // xor-tree combine in np order (validated chain, per quad)
        const int h = ql >> 3, j = ql & 7;
        float v0 = zr[h * 128 + j];
        float r = __fmul_rn(v0, v0);
        #pragma unroll
        for (int t2 = 1; t2 < 16; ++t2) {
            const float v = zr[h * 128 + j + 8 * t2];
            r = __fadd_rn(r, __fmul_rn(v, v));
        }
        { float v = __shfl_xor(r, 1); r = __fadd_rn(r, v); }
        { float v = __shfl_xor(r, 2); r = __fadd_rn(r, v); }
        { float v = __shfl_xor(r, 4); r = __fadd_rn(r, v); }
        const float z2n = __fadd_rn(__shfl(r, quad * 16), __shfl(r, quad * 16 + 8));
        // threshold over this point's 128 group minima (fminf: order-insensitive)
        float mn = fminf(fminf(fminf(a[t][0], a[t][1]), fminf(a[t][2], a[t][3])),
                         fminf(fminf(a[t][4], a[t][5]), fminf(a[t][6], a[t][7])));
        #pragma unroll
        for (int off = 1; off < 16; off <<= 1) mn = fminf(mn, __shfl_xor(mn, off));
        const float thr = mn + MARGIN;
        // per-quad 128-bit candidate mask, group g = i*16 + ql (ascending order kept)
        unsigned long long M0 = 0ull, M1 = 0ull;
        #pragma unroll
        for (int i = 0; i < 8; ++i) {
            const unsigned long long bal = __ballot(a[t][i] <= thr);
            const unsigned long long bits = (bal >> (quad * 16)) & 0xFFFFull;
            if (i < 4) M0 |= bits << (i * 16);
            else       M1 |= bits << ((i - 4) * 16);
        }
        float bs = FLT_MAX; int bk = 0x7FFFFFFF;
        while (__any((M0 | M1) != 0ull)) {
            int myt = -1;                          // quad-uniform next group, ascending
            if (M0) { myt = __ffsll(M0) - 1; M0 &= M0 - 1; }
            else if (M1) { myt = 64 + __ffsll(M1) - 1; M1 &= M1 - 1; }
            if (myt >= 0) {
                const int kg = myt * 16 + ql;
                const float e2k = e2[kg];          // hoisted off the chain's tail
                // permuted layout: quad reads 256 B contiguous per c4 step
                const float4* gp = reinterpret_cast<const float4*>(embp)
                                   + (size_t)myt * 1024 + ql;
                // 8x8 segmented prefetch pipeline: pre[] holds seg s+1's loads
                // in flight while seg s's np-exact fmaf chain retires.
                float4 pre[8];
                #pragma unroll
                for (int s8 = 0; s8 < 8; ++s8) pre[s8] = gp[s8 * 16];
                float dot = 0.f;                   // np-exact ascending-c fmaf chain
                #pragma unroll
                for (int seg = 0; seg < 8; ++seg) {
                    float4 cur[8];
                    #pragma unroll
                    for (int s8 = 0; s8 < 8; ++s8) cur[s8] = pre[s8];
                    if (seg < 7) {
                        #pragma unroll
                        for (int s8 = 0; s8 < 8; ++s8)
                            pre[s8] = gp[(seg + 1) * 128 + s8 * 16];
                    }
                    #pragma unroll
                    for (int s8 = 0; s8 < 8; ++s8) {
                        const int c4 = seg * 8 + s8;
                        const float4 zv = *reinterpret_cast<const float4*>(zr + c4 * 4);
                        dot = fmaf(zv.x, cur[s8].x, dot);
                        dot = fmaf(zv.y, cur[s8].y, dot);
                        dot = fmaf(zv.z, cur[s8].z, dot);
                        dot = fmaf(zv.w, cur[s8].w, dot);
                    }
                }
                const float A = __fadd_rn(z2n, e2k);
                const float s = __fsub_rn(A, __fmul_rn(2.f, dot));
                if (s < bs || (s == bs && kg < bk)) { bs = s; bk = kg; }
            }
        }
        #pragma unroll
        for (int off = 1; off < 16; off <<= 1) {   // lex-min within quad = np.argmin
            const float os = __shfl_xor(bs, off);
            const int ok = __shfl_xor(bk, off);
            if (os < bs || (os == bs && ok < bk)) { bs = os; bk = ok; }
        }
        // gather z_q row (out[n][c] = emb[idx[n]][c]) + loss, float4 per quad-lane
        const float* eq = emb + (size_t)bk * DIM;
        float* op = outf + (size_t)n * DIM;
        #pragma unroll
        for (int jj = 0; jj < 4; ++jj) {
            const int c = (jj * 16 + ql) * 4;
            const float4 q4 = *reinterpret_cast<const float4*>(eq + c);
            f32x4 q; q[0] = q4.x; q[1] = q4.y; q[2] = q4.z; q[3] = q4.w;
            nt_store4(op + c, q);
            float d;
            d = q4.x - zr[c + 0]; lossacc = fmaf(d, d, lossacc);
            d = q4.y - zr[c + 1]; lossacc = fmaf(d, d, lossacc);
            d = q4.z - zr[c + 2]; lossacc = fmaf(d, d, lossacc);
            d = q4.w - zr[c + 3]; lossacc = fmaf(d, d, lossacc);
        }
        if (ql == 0) out_idx[n] = (float)bk;
    }
    #pragma unroll
    for (int off = 1; off < 64; off <<= 1) lossacc += __shfl_xor(lossacc, off);
    if (lane == 0) atomicAdd(&partial[blockIdx.x & 63], lossacc);
}

__global__ void finalize_kernel(const float* __restrict__ partial, float* __restrict__ out_loss) {
    float v = partial[threadIdx.x];          // 64 threads
    #pragma unroll
    for (int off = 1; off < 64; off <<= 1) v += __shfl_xor(v, off);
    if (threadIdx.x == 0)
        *out_loss = v * 1.25f / (float)N_ELEM;   // (1+BETA)*mean
}

extern "C" void kernel_launch(void* const* d_in, const int* in_sizes, int n_in,
                              void* d_out, int out_size, void* d_ws, size_t ws_size,
                              hipStream_t stream) {
    const float* z = (const float*)d_in[0];
    const float* emb = (const float*)d_in[1];
    char* ws = (char*)d_ws;
    float* partial = (float*)(ws + WS_PARTIAL);
    float* e2 = (float*)(ws + WS_E2);
    ushort_t* eb = (ushort_t*)(ws + WS_EB);
    ushort_t* zt = (ushort_t*)(ws + WS_ZT);
    float* tmin = (float*)(ws + WS_TMIN);
    float* embp = (float*)(ws + WS_EMBP);
    float* outf = (float*)d_out;
    float* out_loss = outf + N_ELEM;
    float* out_idx = outf + N_ELEM + 1;

    prep_kernel<<<2560, 256, 0, stream>>>(z, emb, eb, embp, e2, partial, zt);
    screen_kernel<<<4096, 256, 0, stream>>>(zt, eb, e2, tmin);
    exact_kernel<<<N_PTS / 32, 256, 0, stream>>>(z, emb, embp, e2, tmin, outf, out_idx, partial);
    finalize_kernel<<<1, 64, 0, stream>>>(partial, out_loss);
}